// Round 13
// baseline (11044.807 us; speedup 1.0000x reference)
//
#include <hip/hip_runtime.h>

typedef __attribute__((ext_vector_type(4))) float f32x4;
typedef __attribute__((ext_vector_type(8))) __bf16 bf16x8;
typedef __attribute__((ext_vector_type(4))) unsigned short u16x4;
typedef unsigned long long ull;

#define GPAD 40   // GEMM LDS row pad (ushorts)
#define KEEPF(x) asm volatile("" : "+v"(x))
#define PHYS(i) ((i) + (((i) >> 6) << 2))   // +4 words pad per 64 -> conflict-light b128 slices

// ---------------- persistent scratch ----------------
// Tagged u64 words: (step_tag<<32)|f32 bits, agent-scope relaxed atomics (LLC-coherent,
// tag travels with data, no fences). Fan-out-8 replicas: producers store each value to
// 8 replica arrays (lane-parallel); consumer WG polls replica (blockIdx & 7) only.
// g_R layout: [H1:8 | RH1:8 | H2:8 | RH2:8] x 1024 u64.
// g_h1s / g_h2s: write-once rings (slot s tagged s+1); g_h2s feeds the in-flight heads.
__device__ ull g_R[32 * 1024];
__device__ ull g_h1s[1025 * 1024];
__device__ ull g_h2s[1024 * 1024];
__device__ float g_ExW[1024 * 3072];               // [step][z|r|w] layer-1 input terms

#define H1R  0
#define RH1R (8 * 1024)
#define H2R  (16 * 1024)
#define RH2R (24 * 1024)

__device__ __forceinline__ unsigned short f2bf(float x) {
  unsigned u = __builtin_bit_cast(unsigned, x);
  u += 0x7FFFu + ((u >> 16) & 1u);   // RNE
  return (unsigned short)(u >> 16);
}
__device__ __forceinline__ ull packtv(unsigned tag, float v) {
  return ((ull)tag << 32) | (ull)__builtin_bit_cast(unsigned, v);
}
__device__ __forceinline__ ull aload(const ull* p) {
  return __hip_atomic_load(p, __ATOMIC_RELAXED, __HIP_MEMORY_SCOPE_AGENT);
}
__device__ __forceinline__ void astore(ull* p, ull v) {
  __hip_atomic_store(p, v, __ATOMIC_RELAXED, __HIP_MEMORY_SCOPE_AGENT);
}
__device__ __forceinline__ float lo32(ull v) {
  return __builtin_bit_cast(float, (unsigned)v);
}
__device__ __forceinline__ unsigned tagbad4(ull a0, ull a1, ull a2, ull a3, unsigned tg) {
  return ((unsigned)(a0 >> 32) ^ tg) | ((unsigned)(a1 >> 32) ^ tg) |
         ((unsigned)(a2 >> 32) ^ tg) | ((unsigned)(a3 >> 32) ^ tg);
}

// ---------------- fused scan + in-flight heads ----------------
// WGs [0,64): layer 1 — wave = 4 cols x 16 slices-of-64; 192 weight f/thread (pinned).
// WGs [64,192): layer 2 — wave = 2 cols x 32 slices-of-32; 192 weight f/thread (U+W).
// WGs [192,256): persistent head GEMMs consuming the g_h2s ring as rows become ready.
__global__ __launch_bounds__(256, 1) void fused_scan(
    const float* __restrict__ ExW,
    const float* __restrict__ Uz1, const float* __restrict__ Ur1,
    const float* __restrict__ Uw1, const float* __restrict__ bU1,
    const float* __restrict__ Wz2, const float* __restrict__ Wr2,
    const float* __restrict__ Ww2,
    const float* __restrict__ Uz2, const float* __restrict__ Ur2,
    const float* __restrict__ Uw2,
    const float* __restrict__ bW2, const float* __restrict__ bU2,
    const float* __restrict__ Wg, const float* __restrict__ bg,
    const float* __restrict__ Ws, const float* __restrict__ bs,
    float* __restrict__ out)
{
  const int tid = threadIdx.x;
  const int wv = tid >> 6, inw = tid & 63;
  __shared__ __align__(16) char smem[20480];   // scan: 3x1088 f32 (13 KB); heads: As+Bs (20 KB)

  if (blockIdx.x < 64) {
    // ================= layer 1 =================
    float* h_s = (float*)smem;
    float* rh_s = h_s + 1088;
    const int g = blockIdx.x;
    const int rep = g & 7;
    const int c2 = inw >> 4, q = inw & 15;     // wave: 4 cols (c2) x 16 slices (q)
    const int j = g * 16 + wv * 4 + c2;
    const int prj = g * 16 + wv * 4 + (inw >> 4);
    const bool pub = (inw & 15) < 8;
    float uz[64], ur[64], uw[64];
#pragma unroll
    for (int i = 0; i < 64; ++i) uz[i] = Uz1[(size_t)(q * 64 + i) * 1024 + j];
#pragma unroll
    for (int i = 0; i < 64; ++i) ur[i] = Ur1[(size_t)(q * 64 + i) * 1024 + j];
#pragma unroll
    for (int i = 0; i < 64; ++i) uw[i] = Uw1[(size_t)(q * 64 + i) * 1024 + j];
#pragma unroll
    for (int i = 0; i < 64; ++i) { KEEPF(uz[i]); KEEPF(ur[i]); KEEPF(uw[i]); }
    const float bu = bU1[j];

    float xz = 0.f, xr = 0.f, xw = 0.f;
    if (q == 0) { xz = ExW[j]; xr = ExW[1024 + j]; xw = ExW[2048 + j]; }

    float zreg = 0.f, hold = 0.f;
    for (int s = 0; s < 1024; ++s) {
      // ---- poll replica for h tag s ----
      {
        const ull* sl = g_R + H1R + (size_t)rep * 1024 + tid * 4;
        ull a0, a1, a2, a3;
        for (;;) {
          a0 = aload(sl); a1 = aload(sl + 1); a2 = aload(sl + 2); a3 = aload(sl + 3);
          if (!tagbad4(a0, a1, a2, a3, (unsigned)s)) break;
          __builtin_amdgcn_s_sleep(1);
        }
        f32x4 v; v.x = lo32(a0); v.y = lo32(a1); v.z = lo32(a2); v.w = lo32(a3);
        *(f32x4*)&h_s[PHYS(tid * 4)] = v;
      }
      __syncthreads();   // A
      if (q == 0) hold = h_s[PHYS(j)];
      // ---- r-dot (critical) ----
      float ar_ = 0.f;
      {
        const float* hp = h_s + q * 68;
#pragma unroll
        for (int i2 = 0; i2 < 16; ++i2) {
          f32x4 hv = *(const f32x4*)(hp + i2 * 4);
          ar_ = fmaf(ur[i2 * 4 + 0], hv.x, ar_); ar_ = fmaf(ur[i2 * 4 + 1], hv.y, ar_);
          ar_ = fmaf(ur[i2 * 4 + 2], hv.z, ar_); ar_ = fmaf(ur[i2 * 4 + 3], hv.w, ar_);
        }
      }
      ar_ += __shfl_xor(ar_, 1, 64); ar_ += __shfl_xor(ar_, 2, 64);
      ar_ += __shfl_xor(ar_, 4, 64); ar_ += __shfl_xor(ar_, 8, 64);
      float rhv = 0.f;
      if (q == 0) {
        float r = 1.f / (1.f + __expf(-(ar_ + xr)));
        rhv = r * hold;
      }
      // ---- push rh (tag s+1): 8 replicas, lane-parallel ----
      {
        float pvv = __shfl(rhv, inw & 48, 64);
        ull pk = packtv((unsigned)(s + 1), pvv);
        if (pub) astore(g_R + RH1R + (size_t)(inw & 15) * 1024 + prj, pk);
      }
      // ---- z-dot inside the rh wait window ----
      float az_ = 0.f;
      {
        const float* hp = h_s + q * 68;
#pragma unroll
        for (int i2 = 0; i2 < 16; ++i2) {
          f32x4 hv = *(const f32x4*)(hp + i2 * 4);
          az_ = fmaf(uz[i2 * 4 + 0], hv.x, az_); az_ = fmaf(uz[i2 * 4 + 1], hv.y, az_);
          az_ = fmaf(uz[i2 * 4 + 2], hv.z, az_); az_ = fmaf(uz[i2 * 4 + 3], hv.w, az_);
        }
      }
      az_ += __shfl_xor(az_, 1, 64); az_ += __shfl_xor(az_, 2, 64);
      az_ += __shfl_xor(az_, 4, 64); az_ += __shfl_xor(az_, 8, 64);
      if (q == 0) zreg = 1.f / (1.f + __expf(-(az_ + xz)));
      // ---- poll replica for rh tag s+1 ----
      {
        const ull* sl = g_R + RH1R + (size_t)rep * 1024 + tid * 4;
        ull a0, a1, a2, a3;
        const unsigned tg = (unsigned)(s + 1);
        for (;;) {
          a0 = aload(sl); a1 = aload(sl + 1); a2 = aload(sl + 2); a3 = aload(sl + 3);
          if (!tagbad4(a0, a1, a2, a3, tg)) break;
          __builtin_amdgcn_s_sleep(1);
        }
        f32x4 v; v.x = lo32(a0); v.y = lo32(a1); v.z = lo32(a2); v.w = lo32(a3);
        *(f32x4*)&rh_s[PHYS(tid * 4)] = v;
      }
      __syncthreads();   // B
      float aw_ = 0.f;
      {
        const float* rp = rh_s + q * 68;
#pragma unroll
        for (int i2 = 0; i2 < 16; ++i2) {
          f32x4 rv = *(const f32x4*)(rp + i2 * 4);
          aw_ = fmaf(uw[i2 * 4 + 0], rv.x, aw_); aw_ = fmaf(uw[i2 * 4 + 1], rv.y, aw_);
          aw_ = fmaf(uw[i2 * 4 + 2], rv.z, aw_); aw_ = fmaf(uw[i2 * 4 + 3], rv.w, aw_);
        }
      }
      aw_ += __shfl_xor(aw_, 1, 64); aw_ += __shfl_xor(aw_, 2, 64);
      aw_ += __shfl_xor(aw_, 4, 64); aw_ += __shfl_xor(aw_, 8, 64);
      float hn = 0.f;
      if (q == 0) {
        float ht = tanhf(aw_ + xw + bu);
        hn = zreg * ht + (1.f - zreg) * hold;
      }
      // ---- push h (tag s+1): 8 replicas lane-parallel + ring slot for L2 ----
      {
        float pvv = __shfl(hn, inw & 48, 64);
        ull pk = packtv((unsigned)(s + 1), pvv);
        if (pub) astore(g_R + H1R + (size_t)(inw & 15) * 1024 + prj, pk);
        if (q == 0) astore(&g_h1s[(size_t)(s + 1) * 1024 + j], pk);
      }
      // ---- ExW prefetch for s+1 ----
      float nxz = 0.f, nxr = 0.f, nxw = 0.f;
      if (q == 0 && s < 1023) {
        nxz = ExW[(s + 1) * 3072 + j];
        nxr = ExW[(s + 1) * 3072 + 1024 + j];
        nxw = ExW[(s + 1) * 3072 + 2048 + j];
      }
      xz = nxz; xr = nxr; xw = nxw;
    }
  } else if (blockIdx.x < 192) {
    // ================= layer 2 (U+W fused; weights fully in regs) =================
    float* h_s = (float*)smem;
    float* rh_s = h_s + 1088;
    float* x_s = rh_s + 1088;
    const int g = blockIdx.x - 64;
    const int rep = g & 7;
    const int c2 = inw >> 5, q = inw & 31;     // wave: 2 cols (c2) x 32 slices (q)
    const int j = g * 8 + wv * 2 + c2;
    const int sb = q * 32 + ((q >> 1) << 2);   // PHYS base of this thread's 32-slice
    const int prj = g * 8 + wv * 2 + (inw >> 5);
    const bool pub = (inw & 31) < 8;
    float uz[32], ur[32], uw[32], wz[32], wr[32], ww[32];
#pragma unroll
    for (int i = 0; i < 32; ++i) uz[i] = Uz2[(size_t)(q * 32 + i) * 1024 + j];
#pragma unroll
    for (int i = 0; i < 32; ++i) ur[i] = Ur2[(size_t)(q * 32 + i) * 1024 + j];
#pragma unroll
    for (int i = 0; i < 32; ++i) uw[i] = Uw2[(size_t)(q * 32 + i) * 1024 + j];
#pragma unroll
    for (int i = 0; i < 32; ++i) wz[i] = Wz2[(size_t)(q * 32 + i) * 1024 + j];
#pragma unroll
    for (int i = 0; i < 32; ++i) wr[i] = Wr2[(size_t)(q * 32 + i) * 1024 + j];
#pragma unroll
    for (int i = 0; i < 32; ++i) ww[i] = Ww2[(size_t)(q * 32 + i) * 1024 + j];
#pragma unroll
    for (int i = 0; i < 32; ++i) {
      KEEPF(uz[i]); KEEPF(ur[i]); KEEPF(uw[i]);
      KEEPF(wz[i]); KEEPF(wr[i]); KEEPF(ww[i]);
    }
    const float bu = bW2[j] + bU2[j];

    float zreg = 0.f, hold = 0.f;
    for (int s = 0; s < 1024; ++s) {
      // ---- poll replica h2 (tag s) and h1 ring slot s+1 (tag s+1) ----
      {
        const ull* sh = g_R + H2R + (size_t)rep * 1024 + tid * 4;
        const ull* sx = g_h1s + (size_t)(s + 1) * 1024 + tid * 4;
        ull a0, a1, a2, a3, b0, b1, b2, b3;
        const unsigned tg = (unsigned)(s + 1);
        for (;;) {
          a0 = aload(sh); a1 = aload(sh + 1); a2 = aload(sh + 2); a3 = aload(sh + 3);
          b0 = aload(sx); b1 = aload(sx + 1); b2 = aload(sx + 2); b3 = aload(sx + 3);
          unsigned bad = tagbad4(a0, a1, a2, a3, (unsigned)s) | tagbad4(b0, b1, b2, b3, tg);
          if (bad == 0u) break;
          __builtin_amdgcn_s_sleep(2);
        }
        f32x4 v; v.x = lo32(a0); v.y = lo32(a1); v.z = lo32(a2); v.w = lo32(a3);
        *(f32x4*)&h_s[PHYS(tid * 4)] = v;
        f32x4 u4; u4.x = lo32(b0); u4.y = lo32(b1); u4.z = lo32(b2); u4.w = lo32(b3);
        *(f32x4*)&x_s[PHYS(tid * 4)] = u4;
      }
      __syncthreads();   // A
      if (q == 0) hold = h_s[PHYS(j)];
      // ---- r-dot (critical): U_r*h + W_r*x ----
      float ar_ = 0.f;
      {
        const float* hp = h_s + sb;
        const float* xp = x_s + sb;
#pragma unroll
        for (int i2 = 0; i2 < 8; ++i2) {
          f32x4 hv = *(const f32x4*)(hp + i2 * 4);
          f32x4 xv = *(const f32x4*)(xp + i2 * 4);
          ar_ = fmaf(ur[i2 * 4 + 0], hv.x, ar_); ar_ = fmaf(ur[i2 * 4 + 1], hv.y, ar_);
          ar_ = fmaf(ur[i2 * 4 + 2], hv.z, ar_); ar_ = fmaf(ur[i2 * 4 + 3], hv.w, ar_);
          ar_ = fmaf(wr[i2 * 4 + 0], xv.x, ar_); ar_ = fmaf(wr[i2 * 4 + 1], xv.y, ar_);
          ar_ = fmaf(wr[i2 * 4 + 2], xv.z, ar_); ar_ = fmaf(wr[i2 * 4 + 3], xv.w, ar_);
        }
      }
      ar_ += __shfl_xor(ar_, 1, 64); ar_ += __shfl_xor(ar_, 2, 64);
      ar_ += __shfl_xor(ar_, 4, 64); ar_ += __shfl_xor(ar_, 8, 64);
      ar_ += __shfl_xor(ar_, 16, 64);
      float rhv = 0.f;
      if (q == 0) {
        float r = 1.f / (1.f + __expf(-ar_));
        rhv = r * hold;
      }
      // ---- push rh2 (tag s+1): 8 replicas, lane-parallel ----
      {
        float pvv = __shfl(rhv, inw & 32, 64);
        ull pk = packtv((unsigned)(s + 1), pvv);
        if (pub) astore(g_R + RH2R + (size_t)(inw & 31) * 1024 + prj, pk);
      }
      // ---- z-dot inside the rh wait window ----
      float az_ = 0.f;
      {
        const float* hp = h_s + sb;
        const float* xp = x_s + sb;
#pragma unroll
        for (int i2 = 0; i2 < 8; ++i2) {
          f32x4 hv = *(const f32x4*)(hp + i2 * 4);
          f32x4 xv = *(const f32x4*)(xp + i2 * 4);
          az_ = fmaf(uz[i2 * 4 + 0], hv.x, az_); az_ = fmaf(uz[i2 * 4 + 1], hv.y, az_);
          az_ = fmaf(uz[i2 * 4 + 2], hv.z, az_); az_ = fmaf(uz[i2 * 4 + 3], hv.w, az_);
          az_ = fmaf(wz[i2 * 4 + 0], xv.x, az_); az_ = fmaf(wz[i2 * 4 + 1], xv.y, az_);
          az_ = fmaf(wz[i2 * 4 + 2], xv.z, az_); az_ = fmaf(wz[i2 * 4 + 3], xv.w, az_);
        }
      }
      az_ += __shfl_xor(az_, 1, 64); az_ += __shfl_xor(az_, 2, 64);
      az_ += __shfl_xor(az_, 4, 64); az_ += __shfl_xor(az_, 8, 64);
      az_ += __shfl_xor(az_, 16, 64);
      if (q == 0) zreg = 1.f / (1.f + __expf(-az_));
      // ---- poll replica rh2 (tag s+1) ----
      {
        const ull* sl = g_R + RH2R + (size_t)rep * 1024 + tid * 4;
        ull a0, a1, a2, a3;
        const unsigned tg = (unsigned)(s + 1);
        for (;;) {
          a0 = aload(sl); a1 = aload(sl + 1); a2 = aload(sl + 2); a3 = aload(sl + 3);
          if (!tagbad4(a0, a1, a2, a3, tg)) break;
          __builtin_amdgcn_s_sleep(1);
        }
        f32x4 v; v.x = lo32(a0); v.y = lo32(a1); v.z = lo32(a2); v.w = lo32(a3);
        *(f32x4*)&rh_s[PHYS(tid * 4)] = v;
      }
      __syncthreads();   // B
      float aw_ = 0.f;
      {
        const float* rp = rh_s + sb;
        const float* xp = x_s + sb;
#pragma unroll
        for (int i2 = 0; i2 < 8; ++i2) {
          f32x4 rv = *(const f32x4*)(rp + i2 * 4);
          f32x4 xv = *(const f32x4*)(xp + i2 * 4);
          aw_ = fmaf(uw[i2 * 4 + 0], rv.x, aw_); aw_ = fmaf(uw[i2 * 4 + 1], rv.y, aw_);
          aw_ = fmaf(uw[i2 * 4 + 2], rv.z, aw_); aw_ = fmaf(uw[i2 * 4 + 3], rv.w, aw_);
          aw_ = fmaf(ww[i2 * 4 + 0], xv.x, aw_); aw_ = fmaf(ww[i2 * 4 + 1], xv.y, aw_);
          aw_ = fmaf(ww[i2 * 4 + 2], xv.z, aw_); aw_ = fmaf(ww[i2 * 4 + 3], xv.w, aw_);
        }
      }
      aw_ += __shfl_xor(aw_, 1, 64); aw_ += __shfl_xor(aw_, 2, 64);
      aw_ += __shfl_xor(aw_, 4, 64); aw_ += __shfl_xor(aw_, 8, 64);
      aw_ += __shfl_xor(aw_, 16, 64);
      float hn = 0.f;
      if (q == 0) {
        float ht = tanhf(aw_ + bu);
        hn = zreg * ht + (1.f - zreg) * hold;
        astore(&g_h2s[(size_t)s * 1024 + j], packtv((unsigned)(s + 1), hn));  // ring for heads
      }
      // ---- push h2 (tag s+1): 8 replicas, lane-parallel ----
      {
        float pvv = __shfl(hn, inw & 32, 64);
        ull pk = packtv((unsigned)(s + 1), pvv);
        if (pub) astore(g_R + H2R + (size_t)(inw & 31) * 1024 + prj, pk);
      }
    }
  } else {
    // ================= role 2: persistent head GEMMs (hidden under the scan) =========
    // Tiles in row-tile-major order so work tracks scan progress. A = g_h2s ring
    // (tagged, per-slot verified); B = W_g / W_s via nontemporal loads.
    unsigned short* As = (unsigned short*)smem;
    unsigned short* Bs = As + 128 * GPAD;
    const int wid = blockIdx.x - 192;
    const int lane = tid & 63;
    const int wm = wv >> 1, wn = wv & 1;
    const int ar = tid >> 1, ak = (tid & 1) * 16;
    const int bn = (tid >> 3) * 4, bk = (tid & 7) * 4;
    const int TILES = 587 * 8;   // (391 g-tiles + 196 s-tiles) x 8 row-tiles

    for (int t5 = wid; t5 < TILES; t5 += 64) {
      const int rt = t5 / 587, u = t5 % 587;
      const float* B; const float* bias; float* C; int N; int ct;
      if (u < 391) { B = Wg; bias = bg; C = out; N = 50000; ct = u; }
      else         { B = Ws; bias = bs; C = out + 51200000ll; N = 25000; ct = u - 391; }
      const int mbase = rt * 128, nbase = ct * 128;
      const bool nedge = (nbase + 128 > N);

      // coarse gate: own 4 columns of the tile's LAST row published (sleepy poll)
      {
        const ull* gp = g_h2s + (size_t)(mbase + 127) * 1024 + tid * 4;
        const unsigned tg = (unsigned)(mbase + 128);
        for (;;) {
          ull a0 = aload(gp), a1 = aload(gp + 1), a2 = aload(gp + 2), a3 = aload(gp + 3);
          if (!tagbad4(a0, a1, a2, a3, tg)) break;
          __builtin_amdgcn_s_sleep(32);
        }
      }
      __syncthreads();

      f32x4 acc[4][4];
#pragma unroll
      for (int i = 0; i < 4; ++i)
#pragma unroll
        for (int qq = 0; qq < 4; ++qq) acc[i][qq] = (f32x4){0.f, 0.f, 0.f, 0.f};

      for (int ks = 0; ks < 32; ++ks) {   // K = 1024
        const int k0 = ks << 5;
        __syncthreads();
        // stage A from the tagged ring (per-slot verify; normally passes first try)
        {
          const ull* ap = g_h2s + (size_t)(mbase + ar) * 1024 + k0 + ak;
          const unsigned tg = (unsigned)(mbase + ar + 1);
          float v[16];
          for (;;) {
            unsigned bad = 0u;
#pragma unroll
            for (int i = 0; i < 16; ++i) {
              ull w = aload(ap + i);
              bad |= ((unsigned)(w >> 32)) ^ tg;
              v[i] = lo32(w);
            }
            if (bad == 0u) break;
            __builtin_amdgcn_s_sleep(16);
          }
#pragma unroll
          for (int qq = 0; qq < 4; ++qq) {
            u16x4 wq;
            wq.x = f2bf(v[qq * 4 + 0]); wq.y = f2bf(v[qq * 4 + 1]);
            wq.z = f2bf(v[qq * 4 + 2]); wq.w = f2bf(v[qq * 4 + 3]);
            *(u16x4*)&As[ar * GPAD + ak + qq * 4] = wq;
          }
        }
        // stage B (nontemporal: don't evict the scan's hot L3 lines)
        {
          float bv[4][4];
#pragma unroll
          for (int kk = 0; kk < 4; ++kk) {
            const int kglob = k0 + bk + kk;
            if (!nedge) {
              f32x4 t4 = __builtin_nontemporal_load(
                  (const f32x4*)(B + (size_t)kglob * (size_t)N + nbase + bn));
              bv[kk][0] = t4.x; bv[kk][1] = t4.y; bv[kk][2] = t4.z; bv[kk][3] = t4.w;
            } else {
#pragma unroll
              for (int nn = 0; nn < 4; ++nn) {
                int n = nbase + bn + nn;
                bv[kk][nn] = (n < N)
                    ? __builtin_nontemporal_load(B + (size_t)kglob * (size_t)N + n) : 0.f;
              }
            }
          }
#pragma unroll
          for (int nn = 0; nn < 4; ++nn) {
            u16x4 wq;
            wq.x = f2bf(bv[0][nn]); wq.y = f2bf(bv[1][nn]);
            wq.z = f2bf(bv[2][nn]); wq.w = f2bf(bv[3][nn]);
            *(u16x4*)&Bs[(bn + nn) * GPAD + bk] = wq;
          }
        }
        __syncthreads();
        bf16x8 af[4], bfr[4];
        const int fr = lane & 15, fk = (lane >> 4) * 8;
#pragma unroll
        for (int mf = 0; mf < 4; ++mf)
          af[mf] = *(const bf16x8*)&As[(wm * 64 + mf * 16 + fr) * GPAD + fk];
#pragma unroll
        for (int nf = 0; nf < 4; ++nf)
          bfr[nf] = *(const bf16x8*)&Bs[(wn * 64 + nf * 16 + fr) * GPAD + fk];
#pragma unroll
        for (int mf = 0; mf < 4; ++mf)
#pragma unroll
          for (int nf = 0; nf < 4; ++nf)
            acc[mf][nf] = __builtin_amdgcn_mfma_f32_16x16x32_bf16(af[mf], bfr[nf], acc[mf][nf], 0, 0, 0);
      }
      // epilogue
      {
        const int fr = lane & 15, fq = lane >> 4;
#pragma unroll
        for (int nf = 0; nf < 4; ++nf) {
          int col = nbase + wn * 64 + nf * 16 + fr;
          if (col < N) {
            float bb = bias[col];
#pragma unroll
            for (int mf = 0; mf < 4; ++mf) {
              int row0 = mbase + wm * 64 + mf * 16 + fq * 4;
#pragma unroll
              for (int r = 0; r < 4; ++r)
                C[(size_t)(row0 + r) * (size_t)N + col] = acc[mf][nf][r] + bb;
            }
          }
        }
      }
      __syncthreads();
    }
  }
}

// ---------------- bf16 MFMA GEMM (input projections): C = A(f32,[gather])*B + bias ----
__global__ __launch_bounds__(256, 1) void gemm_mfma(
    const float* __restrict__ A, const int* __restrict__ gidx, int lda,
    const float* __restrict__ B, int ldb,
    const float* __restrict__ bias,
    float* __restrict__ C, int ldc, int N, int K)
{
  __shared__ unsigned short As[128 * GPAD];
  __shared__ unsigned short Bs[128 * GPAD];
  const int tid = threadIdx.x;
  const int lane = tid & 63;
  const int wv = tid >> 6;
  const int wm = wv >> 1, wn = wv & 1;
  const int mbase = blockIdx.y * 128, nbase = blockIdx.x * 128;

  f32x4 acc[4][4];
#pragma unroll
  for (int i = 0; i < 4; ++i)
#pragma unroll
    for (int qq = 0; qq < 4; ++qq) acc[i][qq] = (f32x4){0.f, 0.f, 0.f, 0.f};

  const int ar = tid >> 1, ak = (tid & 1) * 16;
  const float* Arow;
  {
    int m = mbase + ar;
    long long gr = gidx ? (long long)gidx[m] : (long long)m;
    Arow = A + (size_t)gr * (size_t)lda;
  }
  const int bn = (tid >> 3) * 4;
  const int bk = (tid & 7) * 4;
  const bool nedge = (nbase + 128 > N);

  const int ksteps = (K + 31) >> 5;
  for (int ks = 0; ks < ksteps; ++ks) {
    const int k0 = ks << 5;
    __syncthreads();
    {
      float v[16];
      const int kg = k0 + ak;
      if (kg + 16 <= K) {
#pragma unroll
        for (int qq = 0; qq < 4; ++qq) {
          f32x4 t = *(const f32x4*)(Arow + kg + qq * 4);
          v[qq * 4 + 0] = t.x; v[qq * 4 + 1] = t.y; v[qq * 4 + 2] = t.z; v[qq * 4 + 3] = t.w;
        }
      } else {
#pragma unroll
        for (int i = 0; i < 16; ++i) v[i] = (kg + i < K) ? Arow[kg + i] : 0.f;
      }
#pragma unroll
      for (int qq = 0; qq < 4; ++qq) {
        u16x4 wq;
        wq.x = f2bf(v[qq * 4 + 0]); wq.y = f2bf(v[qq * 4 + 1]);
        wq.z = f2bf(v[qq * 4 + 2]); wq.w = f2bf(v[qq * 4 + 3]);
        *(u16x4*)&As[ar * GPAD + ak + qq * 4] = wq;
      }
    }
    {
      float bv[4][4];
#pragma unroll
      for (int kk = 0; kk < 4; ++kk) {
        int kglob = k0 + bk + kk;
        if (kglob < K) {
          if (!nedge) {
            f32x4 t = *(const f32x4*)(B + (size_t)kglob * (size_t)ldb + nbase + bn);
            bv[kk][0] = t.x; bv[kk][1] = t.y; bv[kk][2] = t.z; bv[kk][3] = t.w;
          } else {
#pragma unroll
            for (int nn = 0; nn < 4; ++nn) {
              int n = nbase + bn + nn;
              bv[kk][nn] = (n < N) ? B[(size_t)kglob * (size_t)ldb + n] : 0.f;
            }
          }
        } else {
          bv[kk][0] = bv[kk][1] = bv[kk][2] = bv[kk][3] = 0.f;
        }
      }
#pragma unroll
      for (int nn = 0; nn < 4; ++nn) {
        u16x4 wq;
        wq.x = f2bf(bv[0][nn]); wq.y = f2bf(bv[1][nn]);
        wq.z = f2bf(bv[2][nn]); wq.w = f2bf(bv[3][nn]);
        *(u16x4*)&Bs[(bn + nn) * GPAD + bk] = wq;
      }
    }
    __syncthreads();
    bf16x8 af[4], bfr[4];
    const int fr = lane & 15, fk = (lane >> 4) * 8;
#pragma unroll
    for (int mf = 0; mf < 4; ++mf)
      af[mf] = *(const bf16x8*)&As[(wm * 64 + mf * 16 + fr) * GPAD + fk];
#pragma unroll
    for (int nf = 0; nf < 4; ++nf)
      bfr[nf] = *(const bf16x8*)&Bs[(wn * 64 + nf * 16 + fr) * GPAD + fk];
#pragma unroll
    for (int mf = 0; mf < 4; ++mf)
#pragma unroll
      for (int nf = 0; nf < 4; ++nf)
        acc[mf][nf] = __builtin_amdgcn_mfma_f32_16x16x32_bf16(af[mf], bfr[nf], acc[mf][nf], 0, 0, 0);
  }
  const int fr = lane & 15, fq = lane >> 4;
#pragma unroll
  for (int nf = 0; nf < 4; ++nf) {
    int col = nbase + wn * 64 + nf * 16 + fr;
    if (col < N) {
      float bb = bias ? bias[col] : 0.f;
#pragma unroll
      for (int mf = 0; mf < 4; ++mf) {
        int row0 = mbase + wm * 64 + mf * 16 + fq * 4;
#pragma unroll
        for (int r = 0; r < 4; ++r)
          C[(size_t)(row0 + r) * (size_t)ldc + col] = acc[mf][nf][r] + bb;
      }
    }
  }
}

// ---------------- row-wise log-softmax, in place on d_out ----------------
__global__ __launch_bounds__(256, 1) void logsoftmax_kernel(float* __restrict__ out) {
  const int row = blockIdx.x;
  float* p; int len;
  if (row < 1024) { p = out + (size_t)row * 50000u; len = 50000; }
  else            { p = out + 51200000ull + (size_t)(row - 1024) * 25000u; len = 25000; }
  const int tid = threadIdx.x;
  __shared__ float mred[4], sred[4];

  float m = -3.4e38f;
  for (int i = tid * 4; i < len; i += 1024) {
    f32x4 v = *(const f32x4*)(p + i);
    m = fmaxf(m, fmaxf(fmaxf(v.x, v.y), fmaxf(v.z, v.w)));
  }
#pragma unroll
  for (int off = 32; off >= 1; off >>= 1) m = fmaxf(m, __shfl_xor(m, off, 64));
  if ((tid & 63) == 0) mred[tid >> 6] = m;
  __syncthreads();
  m = fmaxf(fmaxf(mred[0], mred[1]), fmaxf(mred[2], mred[3]));

  float ssum = 0.f;
  for (int i = tid * 4; i < len; i += 1024) {
    f32x4 v = *(const f32x4*)(p + i);
    ssum += __expf(v.x - m) + __expf(v.y - m) + __expf(v.z - m) + __expf(v.w - m);
  }
#pragma unroll
  for (int off = 32; off >= 1; off >>= 1) ssum += __shfl_xor(ssum, off, 64);
  if ((tid & 63) == 0) sred[tid >> 6] = ssum;
  __syncthreads();
  const float lse = m + logf(sred[0] + sred[1] + sred[2] + sred[3]);

  for (int i = tid * 4; i < len; i += 1024) {
    f32x4 v = *(const f32x4*)(p + i);
    v.x -= lse; v.y -= lse; v.z -= lse; v.w -= lse;
    *(f32x4*)(p + i) = v;
  }
}

// ---------------- launch ----------------
extern "C" void kernel_launch(void* const* d_in, const int* in_sizes, int n_in,
                              void* d_out, int out_size, void* d_ws, size_t ws_size,
                              hipStream_t stream) {
  (void)in_sizes; (void)n_in; (void)out_size; (void)d_ws; (void)ws_size;
  const int*   x_idx = (const int*)  d_in[0];
  const float* X     = (const float*)d_in[1];
  const float* W_z_1 = (const float*)d_in[2];
  const float* U_z_1 = (const float*)d_in[3];
  const float* W_r_1 = (const float*)d_in[4];
  const float* U_r_1 = (const float*)d_in[5];
  const float* W_1   = (const float*)d_in[6];
  const float* b_W_1 = (const float*)d_in[7];
  const float* U_1   = (const float*)d_in[8];
  const float* b_U_1 = (const float*)d_in[9];
  const float* W_z_2 = (const float*)d_in[10];
  const float* U_z_2 = (const float*)d_in[11];
  const float* W_r_2 = (const float*)d_in[12];
  const float* U_r_2 = (const float*)d_in[13];
  const float* W_2   = (const float*)d_in[14];
  const float* b_W_2 = (const float*)d_in[15];
  const float* U_2   = (const float*)d_in[16];
  const float* b_U_2 = (const float*)d_in[17];
  const float* W_g   = (const float*)d_in[18];
  const float* b_g   = (const float*)d_in[19];
  const float* W_s   = (const float*)d_in[20];
  const float* b_s   = (const float*)d_in[21];
  float* out = (float*)d_out;

  float* ExW;
  ull *R, *h1s, *h2s;
  hipGetSymbolAddress((void**)&ExW, HIP_SYMBOL(g_ExW));
  hipGetSymbolAddress((void**)&R, HIP_SYMBOL(g_R));
  hipGetSymbolAddress((void**)&h1s, HIP_SYMBOL(g_h1s));
  hipGetSymbolAddress((void**)&h2s, HIP_SYMBOL(g_h2s));

  const dim3 blk(256);

  // reset sync state: replicas (tag0 = h(0)=0 valid) + rings (stale tags would match)
  hipMemsetAsync(R, 0, 32ull * 1024 * sizeof(ull), stream);
  hipMemsetAsync(h1s, 0, 1025ull * 1024 * sizeof(ull), stream);
  hipMemsetAsync(h2s, 0, 1024ull * 1024 * sizeof(ull), stream);

  // layer-1 input projections: E(=X[idx]) @ {W_z_1, W_r_1, W_1}  -> g_ExW
  gemm_mfma<<<dim3(8, 8), blk, 0, stream>>>(X, x_idx, 300, W_z_1, 1024, nullptr, ExW + 0,    3072, 1024, 300);
  gemm_mfma<<<dim3(8, 8), blk, 0, stream>>>(X, x_idx, 300, W_r_1, 1024, nullptr, ExW + 1024, 3072, 1024, 300);
  gemm_mfma<<<dim3(8, 8), blk, 0, stream>>>(X, x_idx, 300, W_1,   1024, b_W_1,   ExW + 2048, 3072, 1024, 300);

  // fused scan + in-flight heads (64 L1 + 128 L2 + 64 head WGs)
  fused_scan<<<dim3(256), blk, 0, stream>>>(
      ExW, U_z_1, U_r_1, U_1, b_U_1,
      W_z_2, W_r_2, W_2, U_z_2, U_r_2, U_2, b_W_2, b_U_2,
      W_g, b_g, W_s, b_s, out);

  // in-place log-softmax
  logsoftmax_kernel<<<dim3(2048), blk, 0, stream>>>(out);
}

// Round 14
// 6428.988 us; speedup vs baseline: 1.7180x; 1.7180x over previous
//
#include <hip/hip_runtime.h>

typedef __attribute__((ext_vector_type(4))) float f32x4;
typedef __attribute__((ext_vector_type(8))) __bf16 bf16x8;
typedef __attribute__((ext_vector_type(4))) unsigned short u16x4;
typedef unsigned long long ull;

#define GPAD 40   // GEMM LDS row pad (ushorts)
#define KEEPF(x) asm volatile("" : "+v"(x))
#define PHYS(i) ((i) + (((i) >> 6) << 2))   // +4 words pad per 64 -> conflict-light b128 slices

// ---------------- persistent scratch ----------------
// Tagged u64 words: (step_tag<<32)|f32 bits, agent-scope relaxed atomics (LLC-coherent,
// tag travels with data, no fences). Fan-out-8 replicas: producers store each value to
// 8 replica arrays (lane-parallel: one store instruction per wave); consumer WG polls
// replica (blockIdx & 7) only. g_R layout: [H1:8 | RH1:8 | H2:8 | RH2:8] x 1024 u64.
__device__ ull g_R[32 * 1024];
__device__ ull g_h1s[1025 * 1024];  // write-once ring for L2's h1 input
__device__ float g_ExW[1024 * 3072];               // [step][z|r|w] layer-1 input terms
__device__ float g_hs2[1024 * 1024];

#define H1R  0
#define RH1R (8 * 1024)
#define H2R  (16 * 1024)
#define RH2R (24 * 1024)

__device__ __forceinline__ unsigned short f2bf(float x) {
  unsigned u = __builtin_bit_cast(unsigned, x);
  u += 0x7FFFu + ((u >> 16) & 1u);   // RNE
  return (unsigned short)(u >> 16);
}
__device__ __forceinline__ ull packtv(unsigned tag, float v) {
  return ((ull)tag << 32) | (ull)__builtin_bit_cast(unsigned, v);
}
__device__ __forceinline__ ull aload(const ull* p) {
  return __hip_atomic_load(p, __ATOMIC_RELAXED, __HIP_MEMORY_SCOPE_AGENT);
}
__device__ __forceinline__ void astore(ull* p, ull v) {
  __hip_atomic_store(p, v, __ATOMIC_RELAXED, __HIP_MEMORY_SCOPE_AGENT);
}
__device__ __forceinline__ float lo32(ull v) {
  return __builtin_bit_cast(float, (unsigned)v);
}

// ---------------- fused 2-layer persistent GRU scan ----------------
// WGs [0,64): layer 1 — wave = 4 cols x 16 slices-of-64; 192 weight f/thread.
// WGs [64,192): layer 2 — wave = 2 cols x 32 slices-of-32; 192 weight f/thread (U+W).
// In-wave shfl reduction, 2 barriers/step, z-dot in the rh wait window.
__global__ __launch_bounds__(256, 1) void fused_scan(
    const float* __restrict__ ExW,
    const float* __restrict__ Uz1, const float* __restrict__ Ur1,
    const float* __restrict__ Uw1, const float* __restrict__ bU1,
    const float* __restrict__ Wz2, const float* __restrict__ Wr2,
    const float* __restrict__ Ww2,
    const float* __restrict__ Uz2, const float* __restrict__ Ur2,
    const float* __restrict__ Uw2,
    const float* __restrict__ bW2, const float* __restrict__ bU2,
    float* __restrict__ hs2)
{
  const int tid = threadIdx.x;
  const int wv = tid >> 6, inw = tid & 63;
  __shared__ __align__(16) float h_s[1088];
  __shared__ __align__(16) float rh_s[1088];
  __shared__ __align__(16) float x_s[1088];

  if (blockIdx.x < 64) {
    // ================= layer 1 =================
    const int g = blockIdx.x;
    const int rep = g & 7;
    const int c2 = inw >> 4, q = inw & 15;     // wave: 4 cols (c2) x 16 slices (q)
    const int j = g * 16 + wv * 4 + c2;
    // replica-publish mapping: this lane stores replica (inw&15) of column (inw>>4)
    const int prj = g * 16 + wv * 4 + (inw >> 4);
    const bool pub = (inw & 15) < 8;
    float uz[64], ur[64], uw[64];
#pragma unroll
    for (int i = 0; i < 64; ++i) uz[i] = Uz1[(size_t)(q * 64 + i) * 1024 + j];
#pragma unroll
    for (int i = 0; i < 64; ++i) ur[i] = Ur1[(size_t)(q * 64 + i) * 1024 + j];
#pragma unroll
    for (int i = 0; i < 64; ++i) uw[i] = Uw1[(size_t)(q * 64 + i) * 1024 + j];
#pragma unroll
    for (int i = 0; i < 64; ++i) { KEEPF(uz[i]); KEEPF(ur[i]); KEEPF(uw[i]); }
    const float bu = bU1[j];

    float xz = 0.f, xr = 0.f, xw = 0.f;
    if (q == 0) { xz = ExW[j]; xr = ExW[1024 + j]; xw = ExW[2048 + j]; }

    float zreg = 0.f, hold = 0.f;
    for (int s = 0; s < 1024; ++s) {
      // ---- poll replica for h tag s ----
      {
        const ull* sl = g_R + H1R + (size_t)rep * 1024 + tid * 4;
        ull a0, a1, a2, a3;
        for (;;) {
          a0 = aload(sl); a1 = aload(sl + 1); a2 = aload(sl + 2); a3 = aload(sl + 3);
          unsigned bad = ((unsigned)(a0 >> 32) ^ (unsigned)s) | ((unsigned)(a1 >> 32) ^ (unsigned)s) |
                         ((unsigned)(a2 >> 32) ^ (unsigned)s) | ((unsigned)(a3 >> 32) ^ (unsigned)s);
          if (bad == 0u) break;
          __builtin_amdgcn_s_sleep(1);
        }
        f32x4 v; v.x = lo32(a0); v.y = lo32(a1); v.z = lo32(a2); v.w = lo32(a3);
        *(f32x4*)&h_s[PHYS(tid * 4)] = v;
      }
      __syncthreads();   // A
      if (q == 0) hold = h_s[PHYS(j)];
      // ---- r-dot (critical) ----
      float ar_ = 0.f;
      {
        const float* hp = h_s + q * 68;
#pragma unroll
        for (int i2 = 0; i2 < 16; ++i2) {
          f32x4 hv = *(const f32x4*)(hp + i2 * 4);
          ar_ = fmaf(ur[i2 * 4 + 0], hv.x, ar_); ar_ = fmaf(ur[i2 * 4 + 1], hv.y, ar_);
          ar_ = fmaf(ur[i2 * 4 + 2], hv.z, ar_); ar_ = fmaf(ur[i2 * 4 + 3], hv.w, ar_);
        }
      }
      ar_ += __shfl_xor(ar_, 1, 64); ar_ += __shfl_xor(ar_, 2, 64);
      ar_ += __shfl_xor(ar_, 4, 64); ar_ += __shfl_xor(ar_, 8, 64);
      float rhv = 0.f;
      if (q == 0) {
        float r = 1.f / (1.f + __expf(-(ar_ + xr)));
        rhv = r * hold;
      }
      // ---- push rh (tag s+1): 8 replicas, lane-parallel ----
      {
        float pvv = __shfl(rhv, inw & 48, 64);
        ull pk = packtv((unsigned)(s + 1), pvv);
        if (pub) astore(g_R + RH1R + (size_t)(inw & 15) * 1024 + prj, pk);
      }
      // ---- z-dot inside the rh wait window ----
      float az_ = 0.f;
      {
        const float* hp = h_s + q * 68;
#pragma unroll
        for (int i2 = 0; i2 < 16; ++i2) {
          f32x4 hv = *(const f32x4*)(hp + i2 * 4);
          az_ = fmaf(uz[i2 * 4 + 0], hv.x, az_); az_ = fmaf(uz[i2 * 4 + 1], hv.y, az_);
          az_ = fmaf(uz[i2 * 4 + 2], hv.z, az_); az_ = fmaf(uz[i2 * 4 + 3], hv.w, az_);
        }
      }
      az_ += __shfl_xor(az_, 1, 64); az_ += __shfl_xor(az_, 2, 64);
      az_ += __shfl_xor(az_, 4, 64); az_ += __shfl_xor(az_, 8, 64);
      if (q == 0) zreg = 1.f / (1.f + __expf(-(az_ + xz)));
      // ---- poll replica for rh tag s+1 ----
      {
        const ull* sl = g_R + RH1R + (size_t)rep * 1024 + tid * 4;
        ull a0, a1, a2, a3;
        const unsigned tg = (unsigned)(s + 1);
        for (;;) {
          a0 = aload(sl); a1 = aload(sl + 1); a2 = aload(sl + 2); a3 = aload(sl + 3);
          unsigned bad = ((unsigned)(a0 >> 32) ^ tg) | ((unsigned)(a1 >> 32) ^ tg) |
                         ((unsigned)(a2 >> 32) ^ tg) | ((unsigned)(a3 >> 32) ^ tg);
          if (bad == 0u) break;
          __builtin_amdgcn_s_sleep(1);
        }
        f32x4 v; v.x = lo32(a0); v.y = lo32(a1); v.z = lo32(a2); v.w = lo32(a3);
        *(f32x4*)&rh_s[PHYS(tid * 4)] = v;
      }
      __syncthreads();   // B
      float aw_ = 0.f;
      {
        const float* rp = rh_s + q * 68;
#pragma unroll
        for (int i2 = 0; i2 < 16; ++i2) {
          f32x4 rv = *(const f32x4*)(rp + i2 * 4);
          aw_ = fmaf(uw[i2 * 4 + 0], rv.x, aw_); aw_ = fmaf(uw[i2 * 4 + 1], rv.y, aw_);
          aw_ = fmaf(uw[i2 * 4 + 2], rv.z, aw_); aw_ = fmaf(uw[i2 * 4 + 3], rv.w, aw_);
        }
      }
      aw_ += __shfl_xor(aw_, 1, 64); aw_ += __shfl_xor(aw_, 2, 64);
      aw_ += __shfl_xor(aw_, 4, 64); aw_ += __shfl_xor(aw_, 8, 64);
      float hn = 0.f;
      if (q == 0) {
        float ht = tanhf(aw_ + xw + bu);
        hn = zreg * ht + (1.f - zreg) * hold;
      }
      // ---- push h (tag s+1): 8 replicas lane-parallel + ring slot for L2 ----
      {
        float pvv = __shfl(hn, inw & 48, 64);
        ull pk = packtv((unsigned)(s + 1), pvv);
        if (pub) astore(g_R + H1R + (size_t)(inw & 15) * 1024 + prj, pk);
        if (q == 0) astore(&g_h1s[(size_t)(s + 1) * 1024 + j], pk);
      }
      // ---- ExW prefetch for s+1 ----
      float nxz = 0.f, nxr = 0.f, nxw = 0.f;
      if (q == 0 && s < 1023) {
        nxz = ExW[(s + 1) * 3072 + j];
        nxr = ExW[(s + 1) * 3072 + 1024 + j];
        nxw = ExW[(s + 1) * 3072 + 2048 + j];
      }
      xz = nxz; xr = nxr; xw = nxw;
    }
  } else {
    // ================= layer 2 (U+W fused; weights fully in regs) =================
    const int g = blockIdx.x - 64;
    const int rep = g & 7;
    const int c2 = inw >> 5, q = inw & 31;     // wave: 2 cols (c2) x 32 slices (q)
    const int j = g * 8 + wv * 2 + c2;
    const int sb = q * 32 + ((q >> 1) << 2);   // PHYS base of this thread's 32-slice
    const int prj = g * 8 + wv * 2 + (inw >> 5);
    const bool pub = (inw & 31) < 8;
    float uz[32], ur[32], uw[32], wz[32], wr[32], ww[32];
#pragma unroll
    for (int i = 0; i < 32; ++i) uz[i] = Uz2[(size_t)(q * 32 + i) * 1024 + j];
#pragma unroll
    for (int i = 0; i < 32; ++i) ur[i] = Ur2[(size_t)(q * 32 + i) * 1024 + j];
#pragma unroll
    for (int i = 0; i < 32; ++i) uw[i] = Uw2[(size_t)(q * 32 + i) * 1024 + j];
#pragma unroll
    for (int i = 0; i < 32; ++i) wz[i] = Wz2[(size_t)(q * 32 + i) * 1024 + j];
#pragma unroll
    for (int i = 0; i < 32; ++i) wr[i] = Wr2[(size_t)(q * 32 + i) * 1024 + j];
#pragma unroll
    for (int i = 0; i < 32; ++i) ww[i] = Ww2[(size_t)(q * 32 + i) * 1024 + j];
#pragma unroll
    for (int i = 0; i < 32; ++i) {
      KEEPF(uz[i]); KEEPF(ur[i]); KEEPF(uw[i]);
      KEEPF(wz[i]); KEEPF(wr[i]); KEEPF(ww[i]);
    }
    const float bu = bW2[j] + bU2[j];

    float zreg = 0.f, hold = 0.f;
    for (int s = 0; s < 1024; ++s) {
      // ---- poll replica h2 (tag s) and h1 ring slot s+1 (tag s+1) ----
      {
        const ull* sh = g_R + H2R + (size_t)rep * 1024 + tid * 4;
        const ull* sx = g_h1s + (size_t)(s + 1) * 1024 + tid * 4;
        ull a0, a1, a2, a3, b0, b1, b2, b3;
        const unsigned tg = (unsigned)(s + 1);
        for (;;) {
          a0 = aload(sh); a1 = aload(sh + 1); a2 = aload(sh + 2); a3 = aload(sh + 3);
          b0 = aload(sx); b1 = aload(sx + 1); b2 = aload(sx + 2); b3 = aload(sx + 3);
          unsigned bad = ((unsigned)(a0 >> 32) ^ (unsigned)s) | ((unsigned)(a1 >> 32) ^ (unsigned)s) |
                         ((unsigned)(a2 >> 32) ^ (unsigned)s) | ((unsigned)(a3 >> 32) ^ (unsigned)s) |
                         ((unsigned)(b0 >> 32) ^ tg) | ((unsigned)(b1 >> 32) ^ tg) |
                         ((unsigned)(b2 >> 32) ^ tg) | ((unsigned)(b3 >> 32) ^ tg);
          if (bad == 0u) break;
          __builtin_amdgcn_s_sleep(2);
        }
        f32x4 v; v.x = lo32(a0); v.y = lo32(a1); v.z = lo32(a2); v.w = lo32(a3);
        *(f32x4*)&h_s[PHYS(tid * 4)] = v;
        f32x4 u4; u4.x = lo32(b0); u4.y = lo32(b1); u4.z = lo32(b2); u4.w = lo32(b3);
        *(f32x4*)&x_s[PHYS(tid * 4)] = u4;
      }
      __syncthreads();   // A
      if (q == 0) hold = h_s[PHYS(j)];
      // ---- r-dot (critical): U_r*h + W_r*x ----
      float ar_ = 0.f;
      {
        const float* hp = h_s + sb;
        const float* xp = x_s + sb;
#pragma unroll
        for (int i2 = 0; i2 < 8; ++i2) {
          f32x4 hv = *(const f32x4*)(hp + i2 * 4);
          f32x4 xv = *(const f32x4*)(xp + i2 * 4);
          ar_ = fmaf(ur[i2 * 4 + 0], hv.x, ar_); ar_ = fmaf(ur[i2 * 4 + 1], hv.y, ar_);
          ar_ = fmaf(ur[i2 * 4 + 2], hv.z, ar_); ar_ = fmaf(ur[i2 * 4 + 3], hv.w, ar_);
          ar_ = fmaf(wr[i2 * 4 + 0], xv.x, ar_); ar_ = fmaf(wr[i2 * 4 + 1], xv.y, ar_);
          ar_ = fmaf(wr[i2 * 4 + 2], xv.z, ar_); ar_ = fmaf(wr[i2 * 4 + 3], xv.w, ar_);
        }
      }
      ar_ += __shfl_xor(ar_, 1, 64); ar_ += __shfl_xor(ar_, 2, 64);
      ar_ += __shfl_xor(ar_, 4, 64); ar_ += __shfl_xor(ar_, 8, 64);
      ar_ += __shfl_xor(ar_, 16, 64);
      float rhv = 0.f;
      if (q == 0) {
        float r = 1.f / (1.f + __expf(-ar_));
        rhv = r * hold;
      }
      // ---- push rh2 (tag s+1): 8 replicas, lane-parallel ----
      {
        float pvv = __shfl(rhv, inw & 32, 64);
        ull pk = packtv((unsigned)(s + 1), pvv);
        if (pub) astore(g_R + RH2R + (size_t)(inw & 31) * 1024 + prj, pk);
      }
      // ---- z-dot inside the rh wait window ----
      float az_ = 0.f;
      {
        const float* hp = h_s + sb;
        const float* xp = x_s + sb;
#pragma unroll
        for (int i2 = 0; i2 < 8; ++i2) {
          f32x4 hv = *(const f32x4*)(hp + i2 * 4);
          f32x4 xv = *(const f32x4*)(xp + i2 * 4);
          az_ = fmaf(uz[i2 * 4 + 0], hv.x, az_); az_ = fmaf(uz[i2 * 4 + 1], hv.y, az_);
          az_ = fmaf(uz[i2 * 4 + 2], hv.z, az_); az_ = fmaf(uz[i2 * 4 + 3], hv.w, az_);
          az_ = fmaf(wz[i2 * 4 + 0], xv.x, az_); az_ = fmaf(wz[i2 * 4 + 1], xv.y, az_);
          az_ = fmaf(wz[i2 * 4 + 2], xv.z, az_); az_ = fmaf(wz[i2 * 4 + 3], xv.w, az_);
        }
      }
      az_ += __shfl_xor(az_, 1, 64); az_ += __shfl_xor(az_, 2, 64);
      az_ += __shfl_xor(az_, 4, 64); az_ += __shfl_xor(az_, 8, 64);
      az_ += __shfl_xor(az_, 16, 64);
      if (q == 0) zreg = 1.f / (1.f + __expf(-az_));
      // ---- poll replica rh2 (tag s+1) ----
      {
        const ull* sl = g_R + RH2R + (size_t)rep * 1024 + tid * 4;
        ull a0, a1, a2, a3;
        const unsigned tg = (unsigned)(s + 1);
        for (;;) {
          a0 = aload(sl); a1 = aload(sl + 1); a2 = aload(sl + 2); a3 = aload(sl + 3);
          unsigned bad = ((unsigned)(a0 >> 32) ^ tg) | ((unsigned)(a1 >> 32) ^ tg) |
                         ((unsigned)(a2 >> 32) ^ tg) | ((unsigned)(a3 >> 32) ^ tg);
          if (bad == 0u) break;
          __builtin_amdgcn_s_sleep(1);
        }
        f32x4 v; v.x = lo32(a0); v.y = lo32(a1); v.z = lo32(a2); v.w = lo32(a3);
        *(f32x4*)&rh_s[PHYS(tid * 4)] = v;
      }
      __syncthreads();   // B
      float aw_ = 0.f;
      {
        const float* rp = rh_s + sb;
        const float* xp = x_s + sb;
#pragma unroll
        for (int i2 = 0; i2 < 8; ++i2) {
          f32x4 rv = *(const f32x4*)(rp + i2 * 4);
          f32x4 xv = *(const f32x4*)(xp + i2 * 4);
          aw_ = fmaf(uw[i2 * 4 + 0], rv.x, aw_); aw_ = fmaf(uw[i2 * 4 + 1], rv.y, aw_);
          aw_ = fmaf(uw[i2 * 4 + 2], rv.z, aw_); aw_ = fmaf(uw[i2 * 4 + 3], rv.w, aw_);
          aw_ = fmaf(ww[i2 * 4 + 0], xv.x, aw_); aw_ = fmaf(ww[i2 * 4 + 1], xv.y, aw_);
          aw_ = fmaf(ww[i2 * 4 + 2], xv.z, aw_); aw_ = fmaf(ww[i2 * 4 + 3], xv.w, aw_);
        }
      }
      aw_ += __shfl_xor(aw_, 1, 64); aw_ += __shfl_xor(aw_, 2, 64);
      aw_ += __shfl_xor(aw_, 4, 64); aw_ += __shfl_xor(aw_, 8, 64);
      aw_ += __shfl_xor(aw_, 16, 64);
      float hn = 0.f;
      if (q == 0) {
        float ht = tanhf(aw_ + bu);
        hn = zreg * ht + (1.f - zreg) * hold;
        hs2[(size_t)s * 1024 + j] = hn;
      }
      // ---- push h2 (tag s+1): 8 replicas, lane-parallel ----
      {
        float pvv = __shfl(hn, inw & 32, 64);
        ull pk = packtv((unsigned)(s + 1), pvv);
        if (pub) astore(g_R + H2R + (size_t)(inw & 31) * 1024 + prj, pk);
      }
    }
  }
}

// ---------------- bf16 MFMA GEMM: C[M=1024][N] = A(f32,[gather])*B(f32) + bias ----------------
__global__ __launch_bounds__(256, 1) void gemm_mfma(
    const float* __restrict__ A, const int* __restrict__ gidx, int lda,
    const float* __restrict__ B, int ldb,
    const float* __restrict__ bias,
    float* __restrict__ C, int ldc, int N, int K)
{
  __shared__ unsigned short As[128 * GPAD];
  __shared__ unsigned short Bs[128 * GPAD];
  const int tid = threadIdx.x;
  const int lane = tid & 63;
  const int wv = tid >> 6;
  const int wm = wv >> 1, wn = wv & 1;
  const int mbase = blockIdx.y * 128, nbase = blockIdx.x * 128;

  f32x4 acc[4][4];
#pragma unroll
  for (int i = 0; i < 4; ++i)
#pragma unroll
    for (int qq = 0; qq < 4; ++qq) acc[i][qq] = (f32x4){0.f, 0.f, 0.f, 0.f};

  const int ar = tid >> 1, ak = (tid & 1) * 16;
  const float* Arow;
  {
    int m = mbase + ar;
    long long gr = gidx ? (long long)gidx[m] : (long long)m;
    Arow = A + (size_t)gr * (size_t)lda;
  }
  const int bn = (tid >> 3) * 4;
  const int bk = (tid & 7) * 4;
  const bool nedge = (nbase + 128 > N);

  const int ksteps = (K + 31) >> 5;
  for (int ks = 0; ks < ksteps; ++ks) {
    const int k0 = ks << 5;
    __syncthreads();
    {
      float v[16];
      const int kg = k0 + ak;
      if (kg + 16 <= K) {
#pragma unroll
        for (int qq = 0; qq < 4; ++qq) {
          f32x4 t = *(const f32x4*)(Arow + kg + qq * 4);
          v[qq * 4 + 0] = t.x; v[qq * 4 + 1] = t.y; v[qq * 4 + 2] = t.z; v[qq * 4 + 3] = t.w;
        }
      } else {
#pragma unroll
        for (int i = 0; i < 16; ++i) v[i] = (kg + i < K) ? Arow[kg + i] : 0.f;
      }
#pragma unroll
      for (int qq = 0; qq < 4; ++qq) {
        u16x4 wq;
        wq.x = f2bf(v[qq * 4 + 0]); wq.y = f2bf(v[qq * 4 + 1]);
        wq.z = f2bf(v[qq * 4 + 2]); wq.w = f2bf(v[qq * 4 + 3]);
        *(u16x4*)&As[ar * GPAD + ak + qq * 4] = wq;
      }
    }
    {
      float bv[4][4];
#pragma unroll
      for (int kk = 0; kk < 4; ++kk) {
        int kglob = k0 + bk + kk;
        if (kglob < K) {
          if (!nedge) {
            f32x4 t = *(const f32x4*)(B + (size_t)kglob * (size_t)ldb + nbase + bn);
            bv[kk][0] = t.x; bv[kk][1] = t.y; bv[kk][2] = t.z; bv[kk][3] = t.w;
          } else {
#pragma unroll
            for (int nn = 0; nn < 4; ++nn) {
              int n = nbase + bn + nn;
              bv[kk][nn] = (n < N) ? B[(size_t)kglob * (size_t)ldb + n] : 0.f;
            }
          }
        } else {
          bv[kk][0] = bv[kk][1] = bv[kk][2] = bv[kk][3] = 0.f;
        }
      }
#pragma unroll
      for (int nn = 0; nn < 4; ++nn) {
        u16x4 wq;
        wq.x = f2bf(bv[0][nn]); wq.y = f2bf(bv[1][nn]);
        wq.z = f2bf(bv[2][nn]); wq.w = f2bf(bv[3][nn]);
        *(u16x4*)&Bs[(bn + nn) * GPAD + bk] = wq;
      }
    }
    __syncthreads();
    bf16x8 af[4], bfr[4];
    const int fr = lane & 15, fk = (lane >> 4) * 8;
#pragma unroll
    for (int mf = 0; mf < 4; ++mf)
      af[mf] = *(const bf16x8*)&As[(wm * 64 + mf * 16 + fr) * GPAD + fk];
#pragma unroll
    for (int nf = 0; nf < 4; ++nf)
      bfr[nf] = *(const bf16x8*)&Bs[(wn * 64 + nf * 16 + fr) * GPAD + fk];
#pragma unroll
    for (int mf = 0; mf < 4; ++mf)
#pragma unroll
      for (int nf = 0; nf < 4; ++nf)
        acc[mf][nf] = __builtin_amdgcn_mfma_f32_16x16x32_bf16(af[mf], bfr[nf], acc[mf][nf], 0, 0, 0);
  }
  const int fr = lane & 15, fq = lane >> 4;
#pragma unroll
  for (int nf = 0; nf < 4; ++nf) {
    int col = nbase + wn * 64 + nf * 16 + fr;
    if (col < N) {
      float bb = bias ? bias[col] : 0.f;
#pragma unroll
      for (int mf = 0; mf < 4; ++mf) {
        int row0 = mbase + wm * 64 + mf * 16 + fq * 4;
#pragma unroll
        for (int r = 0; r < 4; ++r)
          C[(size_t)(row0 + r) * (size_t)ldc + col] = acc[mf][nf][r] + bb;
      }
    }
  }
}

// ---------------- row-wise log-softmax, in place on d_out ----------------
__global__ __launch_bounds__(256, 1) void logsoftmax_kernel(float* __restrict__ out) {
  const int row = blockIdx.x;
  float* p; int len;
  if (row < 1024) { p = out + (size_t)row * 50000u; len = 50000; }
  else            { p = out + 51200000ull + (size_t)(row - 1024) * 25000u; len = 25000; }
  const int tid = threadIdx.x;
  __shared__ float mred[4], sred[4];

  float m = -3.4e38f;
  for (int i = tid * 4; i < len; i += 1024) {
    f32x4 v = *(const f32x4*)(p + i);
    m = fmaxf(m, fmaxf(fmaxf(v.x, v.y), fmaxf(v.z, v.w)));
  }
#pragma unroll
  for (int off = 32; off >= 1; off >>= 1) m = fmaxf(m, __shfl_xor(m, off, 64));
  if ((tid & 63) == 0) mred[tid >> 6] = m;
  __syncthreads();
  m = fmaxf(fmaxf(mred[0], mred[1]), fmaxf(mred[2], mred[3]));

  float ssum = 0.f;
  for (int i = tid * 4; i < len; i += 1024) {
    f32x4 v = *(const f32x4*)(p + i);
    ssum += __expf(v.x - m) + __expf(v.y - m) + __expf(v.z - m) + __expf(v.w - m);
  }
#pragma unroll
  for (int off = 32; off >= 1; off >>= 1) ssum += __shfl_xor(ssum, off, 64);
  if ((tid & 63) == 0) sred[tid >> 6] = ssum;
  __syncthreads();
  const float lse = m + logf(sred[0] + sred[1] + sred[2] + sred[3]);

  for (int i = tid * 4; i < len; i += 1024) {
    f32x4 v = *(const f32x4*)(p + i);
    v.x -= lse; v.y -= lse; v.z -= lse; v.w -= lse;
    *(f32x4*)(p + i) = v;
  }
}

// ---------------- launch ----------------
extern "C" void kernel_launch(void* const* d_in, const int* in_sizes, int n_in,
                              void* d_out, int out_size, void* d_ws, size_t ws_size,
                              hipStream_t stream) {
  (void)in_sizes; (void)n_in; (void)out_size; (void)d_ws; (void)ws_size;
  const int*   x_idx = (const int*)  d_in[0];
  const float* X     = (const float*)d_in[1];
  const float* W_z_1 = (const float*)d_in[2];
  const float* U_z_1 = (const float*)d_in[3];
  const float* W_r_1 = (const float*)d_in[4];
  const float* U_r_1 = (const float*)d_in[5];
  const float* W_1   = (const float*)d_in[6];
  const float* b_W_1 = (const float*)d_in[7];
  const float* U_1   = (const float*)d_in[8];
  const float* b_U_1 = (const float*)d_in[9];
  const float* W_z_2 = (const float*)d_in[10];
  const float* U_z_2 = (const float*)d_in[11];
  const float* W_r_2 = (const float*)d_in[12];
  const float* U_r_2 = (const float*)d_in[13];
  const float* W_2   = (const float*)d_in[14];
  const float* b_W_2 = (const float*)d_in[15];
  const float* U_2   = (const float*)d_in[16];
  const float* b_U_2 = (const float*)d_in[17];
  const float* W_g   = (const float*)d_in[18];
  const float* b_g   = (const float*)d_in[19];
  const float* W_s   = (const float*)d_in[20];
  const float* b_s   = (const float*)d_in[21];
  float* out = (float*)d_out;

  float *ExW, *hs2;
  ull *R, *h1s;
  hipGetSymbolAddress((void**)&ExW, HIP_SYMBOL(g_ExW));
  hipGetSymbolAddress((void**)&hs2, HIP_SYMBOL(g_hs2));
  hipGetSymbolAddress((void**)&R, HIP_SYMBOL(g_R));
  hipGetSymbolAddress((void**)&h1s, HIP_SYMBOL(g_h1s));

  const dim3 blk(256);

  // reset sync state: replicas (tag0 = h(0)=0 valid) + ring (stale tags would match)
  hipMemsetAsync(R, 0, 32ull * 1024 * sizeof(ull), stream);
  hipMemsetAsync(h1s, 0, 1025ull * 1024 * sizeof(ull), stream);

  // layer-1 input projections: E(=X[idx]) @ {W_z_1, W_r_1, W_1}  -> g_ExW
  gemm_mfma<<<dim3(8, 8), blk, 0, stream>>>(X, x_idx, 300, W_z_1, 1024, nullptr, ExW + 0,    3072, 1024, 300);
  gemm_mfma<<<dim3(8, 8), blk, 0, stream>>>(X, x_idx, 300, W_r_1, 1024, nullptr, ExW + 1024, 3072, 1024, 300);
  gemm_mfma<<<dim3(8, 8), blk, 0, stream>>>(X, x_idx, 300, W_1,   1024, b_W_1,   ExW + 2048, 3072, 1024, 300);

  // fused two-layer pipelined scan (64 L1-WGs + 128 L2-WGs, 256 thr each)
  fused_scan<<<dim3(192), blk, 0, stream>>>(
      ExW, U_z_1, U_r_1, U_1, b_U_1,
      W_z_2, W_r_2, W_2, U_z_2, U_r_2, U_2, b_W_2, b_U_2, hs2);

  // heads: logits straight into d_out
  gemm_mfma<<<dim3(391, 8), blk, 0, stream>>>(hs2, nullptr, 1024, W_g, 50000, b_g, out,              50000, 50000, 1024);
  gemm_mfma<<<dim3(196, 8), blk, 0, stream>>>(hs2, nullptr, 1024, W_s, 25000, b_s, out + 51200000ll, 25000, 25000, 1024);
  // in-place log-softmax
  logsoftmax_kernel<<<dim3(2048), blk, 0, stream>>>(out);
}